// Round 4
// baseline (529.781 us; speedup 1.0000x reference)
//
#include <hip/hip_runtime.h>

// Problem: B=4, S=2048, D=1024, H=16, HD=64. f32 in/out, fp16 MFMA compute,
// fp32 accumulate. World F: all inputs float32, output float32.
#define B_  4
#define S_  2048
#define D_  1024
#define H_  16
#define HD_ 64
#define BH_ (B_*H_)

typedef _Float16 h16;
typedef _Float16 h8 __attribute__((ext_vector_type(8)));
typedef float    f32x4 __attribute__((ext_vector_type(4)));

// ---------------------------------------------------------------------------
// Convert f32 -> fp16. 8 elems/thread, vectorized.
// ---------------------------------------------------------------------------
__global__ void convert_k(const float* __restrict__ in, h16* __restrict__ out,
                          int n) {
  int idx = (blockIdx.x * 256 + threadIdx.x) * 8;
  if (idx + 8 <= n) {
    float4 f0 = *(const float4*)(in + idx);
    float4 f1 = *(const float4*)(in + idx + 4);
    h16 t[8] = {(h16)f0.x, (h16)f0.y, (h16)f0.z, (h16)f0.w,
                (h16)f1.x, (h16)f1.y, (h16)f1.z, (h16)f1.w};
    *(h8*)(out + idx) = *(h8*)t;
  } else {
    for (int j = idx; j < n; j++) out[j] = (h16)in[j];
  }
}

// ---------------------------------------------------------------------------
// Fused convert + transpose: in (R x C) f32 -> out (C x R) fp16
// ---------------------------------------------------------------------------
__global__ void transpose_conv_k(const float* __restrict__ in,
                                 h16* __restrict__ out, int R, int C) {
  __shared__ h16 tile[32][33];
  int bx = blockIdx.x * 32;  // C base
  int by = blockIdx.y * 32;  // R base
  int tx = threadIdx.x, ty = threadIdx.y;  // block (32, 8)
#pragma unroll
  for (int i = 0; i < 32; i += 8)
    tile[ty + i][tx] = (h16)in[(size_t)(by + ty + i) * C + bx + tx];
  __syncthreads();
#pragma unroll
  for (int i = 0; i < 32; i += 8)
    out[(size_t)(bx + ty + i) * R + by + tx] = tile[tx][ty + i];
}

// ---------------------------------------------------------------------------
// MFMA GEMM: A (M x K) row-major fp16, BT (N x K) row-major fp16, 128x128x32.
// MODE 0: qkv projection -> scatter Q (scaled, +bias), K, Vt(+bias)  [fp16]
// MODE 1: out projection -> d_out (+bias)                            [f32]
// Verified layouts (16x16x32): A[m=lane&15][k=quad*8+j],
// B[n=lane&15][k=quad*8+j], C/D col=lane&15 row=quad*4+reg (dtype-indep).
// ---------------------------------------------------------------------------
template <int MODE>
__global__ __launch_bounds__(256)
void gemm_bt(const h16* __restrict__ A, const h16* __restrict__ BT,
             const h16* __restrict__ bias,
             void* __restrict__ out0v, h16* __restrict__ out1,
             h16* __restrict__ out2, int M, int N, int K) {
  const int tid  = threadIdx.x;
  const int lane = tid & 63;
  const int w    = tid >> 6;
  const int quad = lane >> 4;
  const int l16  = lane & 15;
  const int m0   = blockIdx.x * 128;
  const int n0   = blockIdx.y * 128;

  __shared__ alignas(16) h16 As[128 * 40];  // stride 40 -> 2-way banks (free)
  __shared__ alignas(16) h16 Bs[128 * 40];

  const f32x4 zero = {0.f, 0.f, 0.f, 0.f};
  f32x4 acc[4][4];
#pragma unroll
  for (int i = 0; i < 4; i++)
#pragma unroll
    for (int j = 0; j < 4; j++) acc[i][j] = zero;

  const int wm = (w >> 1) * 64;
  const int wn = (w & 1) * 64;

  for (int kt = 0; kt < K; kt += 32) {
#pragma unroll
    for (int c = 0; c < 2; c++) {
      int idx = tid + c * 256;          // 0..511 chunks of 16B
      int row = idx >> 2;
      int ko  = (idx & 3) * 8;
      *(uint4*)(&As[row * 40 + ko]) =
          *(const uint4*)(&A[(size_t)(m0 + row) * K + kt + ko]);
      *(uint4*)(&Bs[row * 40 + ko]) =
          *(const uint4*)(&BT[(size_t)(n0 + row) * K + kt + ko]);
    }
    __syncthreads();
    h8 af[4], bfr[4];
#pragma unroll
    for (int i = 0; i < 4; i++)
      af[i] = *(const h8*)(&As[(wm + i * 16 + l16) * 40 + quad * 8]);
#pragma unroll
    for (int j = 0; j < 4; j++)
      bfr[j] = *(const h8*)(&Bs[(wn + j * 16 + l16) * 40 + quad * 8]);
#pragma unroll
    for (int i = 0; i < 4; i++)
#pragma unroll
      for (int j = 0; j < 4; j++)
        acc[i][j] = __builtin_amdgcn_mfma_f32_16x16x32_f16(af[i], bfr[j],
                                                           acc[i][j], 0, 0, 0);
    __syncthreads();
  }

  // epilogue
#pragma unroll
  for (int i = 0; i < 4; i++) {
#pragma unroll
    for (int j = 0; j < 4; j++) {
      int n = n0 + wn + j * 16 + l16;
      float bv = (float)bias[n];
#pragma unroll
      for (int r = 0; r < 4; r++) {
        int m = m0 + wm + i * 16 + quad * 4 + r;
        float v = acc[i][j][r] + bv;
        if (MODE == 0) {
          h16* q0 = (h16*)out0v;
          int which = n >> 10;          // 0=Q, 1=K, 2=V
          int h  = (n >> 6) & 15;
          int hd = n & 63;
          int b  = m >> 11;             // S_=2048
          int s  = m & 2047;
          if (which == 0) {
            q0[(((size_t)(b * 16 + h)) * S_ + s) * HD_ + hd] = (h16)(v * 0.125f);
          } else if (which == 1) {
            out1[(((size_t)(b * 16 + h)) * S_ + s) * HD_ + hd] = (h16)v;
          } else {  // V stored transposed: (bh, hd, s)
            out2[(((size_t)(b * 16 + h)) * HD_ + hd) * S_ + s] = (h16)v;
          }
        } else {
          ((float*)out0v)[(size_t)m * N + n] = v;   // f32 output
        }
      }
    }
  }
}

// ---------------------------------------------------------------------------
// Flash attention: grid (S/64, B*H), block 256 (4 waves x 16 q-rows).
// Q,K: (bh, s, hd) fp16 (Q pre-scaled). Vt: (bh, hd, s) fp16.
// Online softmax; -1e30 sentinel for masked keys.
// ---------------------------------------------------------------------------
__global__ __launch_bounds__(256)
void attn_k(const h16* __restrict__ Q, const h16* __restrict__ Km,
            const h16* __restrict__ Vt, const int* __restrict__ mask,
            h16* __restrict__ out) {
  const int tid  = threadIdx.x;
  const int lane = tid & 63;
  const int w    = tid >> 6;
  const int quad = lane >> 4;
  const int l16  = lane & 15;
  const int bh   = blockIdx.y;
  const int b    = bh >> 4, h = bh & 15;
  const int q0   = blockIdx.x * 64 + w * 16;

  const h16* Qh = Q  + (size_t)bh * S_ * HD_;
  const h16* Kh = Km + (size_t)bh * S_ * HD_;
  const h16* Vh = Vt + (size_t)bh * HD_ * S_;
  const int* mb = mask + b * S_;

  __shared__ alignas(16) h16 Ks[32 * 72];      // [key][hd], stride 72
  __shared__ alignas(16) h16 Vs[64 * 40];      // [hd][key], stride 40
  __shared__ alignas(16) h16 Pb[4][16 * 40];   // per-wave P, [qrow][key]

  h8 aq[2];
#pragma unroll
  for (int ks = 0; ks < 2; ks++)
    aq[ks] = *(const h8*)(&Qh[(size_t)(q0 + l16) * 64 + ks * 32 + quad * 8]);

  const f32x4 zero = {0.f, 0.f, 0.f, 0.f};
  f32x4 oacc[4];
#pragma unroll
  for (int j = 0; j < 4; j++) oacc[j] = zero;
  float mst[4], lst[4];
#pragma unroll
  for (int r = 0; r < 4; r++) { mst[r] = -1e30f; lst[r] = 0.f; }

  for (int kb = 0; kb < S_; kb += 32) {
    __syncthreads();  // all waves done with previous Ks/Vs
    {
      int c = tid;
      int key = c >> 3, ko = (c & 7) * 8;   // 32 keys x 64 hd
      *(uint4*)(&Ks[key * 72 + ko]) =
          *(const uint4*)(&Kh[(size_t)(kb + key) * 64 + ko]);
      int hd = c >> 2, vo = (c & 3) * 8;    // 64 hd x 32 keys
      *(uint4*)(&Vs[hd * 40 + vo]) =
          *(const uint4*)(&Vh[(size_t)hd * S_ + kb + vo]);
    }
    __syncthreads();

    // QK^T: two 16-key halves, k=64 over hd in 2 MFMA steps
    f32x4 st[2];
#pragma unroll
    for (int kh = 0; kh < 2; kh++) {
      h8 bk0 = *(const h8*)(&Ks[(kh * 16 + l16) * 72 + quad * 8]);
      h8 bk1 = *(const h8*)(&Ks[(kh * 16 + l16) * 72 + 32 + quad * 8]);
      f32x4 s = zero;
      s = __builtin_amdgcn_mfma_f32_16x16x32_f16(aq[0], bk0, s, 0, 0, 0);
      s = __builtin_amdgcn_mfma_f32_16x16x32_f16(aq[1], bk1, s, 0, 0, 0);
      int mv = mb[kb + kh * 16 + l16];
      if (mv == 0) { s[0] = s[1] = s[2] = s[3] = -1e30f; }
      st[kh] = s;
    }

    // online softmax per q-row (row = quad*4+r; quad's 16 lanes share it)
    float p0[4], p1[4], alpha[4];
#pragma unroll
    for (int r = 0; r < 4; r++) {
      float mx = fmaxf(st[0][r], st[1][r]);
#pragma unroll
      for (int o = 1; o < 16; o <<= 1) mx = fmaxf(mx, __shfl_xor(mx, o, 64));
      float mnew = fmaxf(mst[r], mx);
      alpha[r] = __expf(mst[r] - mnew);
      p0[r] = __expf(st[0][r] - mnew);
      p1[r] = __expf(st[1][r] - mnew);
      float rs = p0[r] + p1[r];
#pragma unroll
      for (int o = 1; o < 16; o <<= 1) rs += __shfl_xor(rs, o, 64);
      lst[r] = lst[r] * alpha[r] + rs;
      mst[r] = mnew;
    }
#pragma unroll
    for (int j = 0; j < 4; j++)
#pragma unroll
      for (int r = 0; r < 4; r++) oacc[j][r] *= alpha[r];

    // P: C-layout -> A-layout via per-wave LDS round-trip (fp16)
    h16* pb = Pb[w];
#pragma unroll
    for (int r = 0; r < 4; r++) {
      pb[(quad * 4 + r) * 40 + l16]      = (h16)p0[r];
      pb[(quad * 4 + r) * 40 + 16 + l16] = (h16)p1[r];
    }
    __syncthreads();
    h8 pa = *(const h8*)(&pb[l16 * 40 + quad * 8]);

    // PV: O(16x64) += P(16x32) * V(32x64), 4 hd-tiles
#pragma unroll
    for (int j = 0; j < 4; j++) {
      h8 bv = *(const h8*)(&Vs[(j * 16 + l16) * 40 + quad * 8]);
      oacc[j] = __builtin_amdgcn_mfma_f32_16x16x32_f16(pa, bv, oacc[j], 0, 0, 0);
    }
  }

  // epilogue: out[b][s][h*64+hd] = O / l   (fp16 intermediate)
#pragma unroll
  for (int j = 0; j < 4; j++)
#pragma unroll
    for (int r = 0; r < 4; r++) {
      int row = q0 + quad * 4 + r;
      float v = oacc[j][r] / lst[r];
      out[((size_t)(b * S_ + row)) * D_ + h * 64 + j * 16 + l16] = (h16)v;
    }
}

// ---------------------------------------------------------------------------
// ws (64 MiB exactly, as fp16 elems): Qb[0,NT) Kb[NT,2NT) Vtb[2NT,3NT)
// R3[3NT,4NT): xc (canonical x, dead before attn) then AOb (attn out).
// WouT aliases Qb (written after attn); boutc aliases Vtb.
// d_out (33.5 MB f32) as early scratch: WinT (3.15M halfs) + binc — both
// dead before gemm<1> writes the f32 output over all of d_out.
// Order: conv(b_in) -> T(w_in) -> conv(x) -> gemm<0> -> attn -> T(w_out)
//        -> conv(b_out) -> gemm<1>
// ---------------------------------------------------------------------------
extern "C" void kernel_launch(void* const* d_in, const int* in_sizes, int n_in,
                              void* d_out, int out_size, void* d_ws,
                              size_t ws_size, hipStream_t stream) {
  const float* x     = (const float*)d_in[0];  // (B,S,D)
  const float* w_in  = (const float*)d_in[1];  // (D, 3D)
  const float* b_in  = (const float*)d_in[2];  // (3D)
  const float* w_out = (const float*)d_in[3];  // (D, D)
  const float* b_out = (const float*)d_in[4];  // (D)
  const int*   mask  = (const int*)d_in[5];    // (B,S) int32

  const size_t NT = (size_t)BH_ * S_ * HD_;    // 8,388,608 elems
  h16* ws    = (h16*)d_ws;
  h16* Qb    = ws;
  h16* Kb    = ws + NT;
  h16* Vtb   = ws + 2 * NT;
  h16* xc    = ws + 3 * NT;      // canonical x, dead before attn
  h16* AOb   = ws + 3 * NT;      // attn output, written after xc dead
  h16* WouT  = Qb;               // (D,D) transposed, written after attn
  h16* boutc = Vtb;              // 1024 elems, written after attn
  h16* WinT  = (h16*)d_out;      // d_out scratch: (3D,D) = 3.15M halfs
  h16* binc  = (h16*)d_out + 3400704;  // d_out scratch: 3072 halfs

  convert_k<<<2, 256, 0, stream>>>(b_in, binc, 3 * D_);
  transpose_conv_k<<<dim3(3 * D_ / 32, D_ / 32), dim3(32, 8), 0, stream>>>(
      w_in, WinT, D_, 3 * D_);
  convert_k<<<(B_ * S_ * D_) / 2048, 256, 0, stream>>>(x, xc, B_ * S_ * D_);

  gemm_bt<0><<<dim3((B_ * S_) / 128, (3 * D_) / 128), 256, 0, stream>>>(
      xc, WinT, binc, Qb, Kb, Vtb, B_ * S_, 3 * D_, D_);

  attn_k<<<dim3(S_ / 64, BH_), 256, 0, stream>>>(Qb, Kb, Vtb, mask, AOb);

  transpose_conv_k<<<dim3(D_ / 32, D_ / 32), dim3(32, 8), 0, stream>>>(
      w_out, WouT, D_, D_);
  convert_k<<<1, 256, 0, stream>>>(b_out, boutc, D_);

  gemm_bt<1><<<dim3((B_ * S_) / 128, D_ / 128), 256, 0, stream>>>(
      AOb, WouT, boutc, d_out, nullptr, nullptr, B_ * S_, D_, D_);
}

// Round 5
// 393.061 us; speedup vs baseline: 1.3478x; 1.3478x over previous
//
#include <hip/hip_runtime.h>

// Problem: B=4, S=2048, D=1024, H=16, HD=64. f32 in/out, fp16 MFMA compute,
// fp32 accumulate. Mask-compacted attention: only valid keys processed.
#define B_  4
#define S_  2048
#define D_  1024
#define H_  16
#define HD_ 64
#define BH_ (B_*H_)

typedef _Float16 h16;
typedef _Float16 h8 __attribute__((ext_vector_type(8)));
typedef float    f32x4 __attribute__((ext_vector_type(4)));

// ---------------------------------------------------------------------------
// Per-batch mask prefix-scan: posmap[b][s] = compacted index (or -1),
// nvalid[b] = count. One block per batch, 256 threads x 8 elems.
// ---------------------------------------------------------------------------
__global__ void maskscan_k(const int* __restrict__ mask,
                           int* __restrict__ posmap, int* __restrict__ nvalid) {
  __shared__ int partial[256];
  int b = blockIdx.x;
  const int* mb = mask + b * S_;
  int t = threadIdx.x;
  int base = t * 8;
  int loc[8], cnt = 0;
#pragma unroll
  for (int j = 0; j < 8; j++) { loc[j] = cnt; cnt += (mb[base + j] != 0); }
  partial[t] = cnt;
  __syncthreads();
  for (int off = 1; off < 256; off <<= 1) {
    int v = (t >= off) ? partial[t - off] : 0;
    __syncthreads();
    partial[t] += v;
    __syncthreads();
  }
  int excl = (t == 0) ? 0 : partial[t - 1];
#pragma unroll
  for (int j = 0; j < 8; j++)
    posmap[b * S_ + base + j] = (mb[base + j] != 0) ? (excl + loc[j]) : -1;
  if (t == 255) nvalid[b] = partial[255];
}

// ---------------------------------------------------------------------------
// Convert f32 -> fp16. 8 elems/thread, vectorized.
// ---------------------------------------------------------------------------
__global__ void convert_k(const float* __restrict__ in, h16* __restrict__ out,
                          int n) {
  int idx = (blockIdx.x * 256 + threadIdx.x) * 8;
  if (idx + 8 <= n) {
    float4 f0 = *(const float4*)(in + idx);
    float4 f1 = *(const float4*)(in + idx + 4);
    h16 t[8] = {(h16)f0.x, (h16)f0.y, (h16)f0.z, (h16)f0.w,
                (h16)f1.x, (h16)f1.y, (h16)f1.z, (h16)f1.w};
    *(h8*)(out + idx) = *(h8*)t;
  } else {
    for (int j = idx; j < n; j++) out[j] = (h16)in[j];
  }
}

// ---------------------------------------------------------------------------
// Fused convert + transpose: in (R x C) f32 -> out (C x R) fp16
// ---------------------------------------------------------------------------
__global__ void transpose_conv_k(const float* __restrict__ in,
                                 h16* __restrict__ out, int R, int C) {
  __shared__ h16 tile[32][33];
  int bx = blockIdx.x * 32;
  int by = blockIdx.y * 32;
  int tx = threadIdx.x, ty = threadIdx.y;  // block (32, 8)
#pragma unroll
  for (int i = 0; i < 32; i += 8)
    tile[ty + i][tx] = (h16)in[(size_t)(by + ty + i) * C + bx + tx];
  __syncthreads();
#pragma unroll
  for (int i = 0; i < 32; i += 8)
    out[(size_t)(bx + ty + i) * R + by + tx] = tile[tx][ty + i];
}

// ---------------------------------------------------------------------------
// MFMA GEMM: A (M x K) row-major fp16, BT (N x K) row-major fp16, 128x128x32.
// MODE 0: qkv proj -> Q (scaled,+bias); K,V scattered through posmap into
//         compacted Kc (bh,pos,hd) / Vtc (bh,hd,pos). Invalid keys dropped.
// MODE 1: out projection -> d_out f32 (+bias)
// ---------------------------------------------------------------------------
template <int MODE>
__global__ __launch_bounds__(256)
void gemm_bt(const h16* __restrict__ A, const h16* __restrict__ BT,
             const h16* __restrict__ bias, const int* __restrict__ posmap,
             void* __restrict__ out0v, h16* __restrict__ out1,
             h16* __restrict__ out2, int M, int N, int K) {
  const int tid  = threadIdx.x;
  const int lane = tid & 63;
  const int w    = tid >> 6;
  const int quad = lane >> 4;
  const int l16  = lane & 15;
  const int m0   = blockIdx.x * 128;
  const int n0   = blockIdx.y * 128;

  __shared__ alignas(16) h16 As[128 * 40];  // stride 40 -> 2-way banks (free)
  __shared__ alignas(16) h16 Bs[128 * 40];

  const f32x4 zero = {0.f, 0.f, 0.f, 0.f};
  f32x4 acc[4][4];
#pragma unroll
  for (int i = 0; i < 4; i++)
#pragma unroll
    for (int j = 0; j < 4; j++) acc[i][j] = zero;

  const int wm = (w >> 1) * 64;
  const int wn = (w & 1) * 64;

  for (int kt = 0; kt < K; kt += 32) {
#pragma unroll
    for (int c = 0; c < 2; c++) {
      int idx = tid + c * 256;
      int row = idx >> 2;
      int ko  = (idx & 3) * 8;
      *(uint4*)(&As[row * 40 + ko]) =
          *(const uint4*)(&A[(size_t)(m0 + row) * K + kt + ko]);
      *(uint4*)(&Bs[row * 40 + ko]) =
          *(const uint4*)(&BT[(size_t)(n0 + row) * K + kt + ko]);
    }
    __syncthreads();
    h8 af[4], bfr[4];
#pragma unroll
    for (int i = 0; i < 4; i++)
      af[i] = *(const h8*)(&As[(wm + i * 16 + l16) * 40 + quad * 8]);
#pragma unroll
    for (int j = 0; j < 4; j++)
      bfr[j] = *(const h8*)(&Bs[(wn + j * 16 + l16) * 40 + quad * 8]);
#pragma unroll
    for (int i = 0; i < 4; i++)
#pragma unroll
      for (int j = 0; j < 4; j++)
        acc[i][j] = __builtin_amdgcn_mfma_f32_16x16x32_f16(af[i], bfr[j],
                                                           acc[i][j], 0, 0, 0);
    __syncthreads();
  }

  // epilogue
#pragma unroll
  for (int i = 0; i < 4; i++) {
#pragma unroll
    for (int j = 0; j < 4; j++) {
      int n = n0 + wn + j * 16 + l16;
      float bv = (float)bias[n];
#pragma unroll
      for (int r = 0; r < 4; r++) {
        int m = m0 + wm + i * 16 + quad * 4 + r;
        float v = acc[i][j][r] + bv;
        if (MODE == 0) {
          h16* q0 = (h16*)out0v;
          int which = n >> 10;          // 0=Q, 1=K, 2=V
          int h  = (n >> 6) & 15;
          int hd = n & 63;
          int b  = m >> 11;             // S_=2048
          int s  = m & 2047;
          if (which == 0) {
            q0[(((size_t)(b * 16 + h)) * S_ + s) * HD_ + hd] = (h16)(v * 0.125f);
          } else {
            int pos = posmap[b * S_ + s];
            if (pos >= 0) {
              if (which == 1)  // compacted K: (bh, pos, hd)
                out1[(((size_t)(b * 16 + h)) * S_ + pos) * HD_ + hd] = (h16)v;
              else             // compacted V^T: (bh, hd, pos)
                out2[(((size_t)(b * 16 + h)) * HD_ + hd) * S_ + pos] = (h16)v;
            }
          }
        } else {
          ((float*)out0v)[(size_t)m * N + n] = v;   // f32 output
        }
      }
    }
  }
}

// ---------------------------------------------------------------------------
// Flash attention over compacted keys: grid (S/64, B*H), block 256
// (4 waves x 16 q-rows). Q: (bh,s,hd) fp16 pre-scaled. Kc: (bh,pos,hd).
// Vtc: (bh,hd,pos). Loop runs kb < nvalid[b]; tail slots masked by index.
// ---------------------------------------------------------------------------
__global__ __launch_bounds__(256)
void attn_k(const h16* __restrict__ Q, const h16* __restrict__ Kc,
            const h16* __restrict__ Vtc, const int* __restrict__ nvalid,
            h16* __restrict__ out) {
  const int tid  = threadIdx.x;
  const int lane = tid & 63;
  const int w    = tid >> 6;
  const int quad = lane >> 4;
  const int l16  = lane & 15;
  const int bh   = blockIdx.y;
  const int b    = bh >> 4, h = bh & 15;
  const int q0   = blockIdx.x * 64 + w * 16;
  const int nv   = nvalid[b];

  const h16* Qh = Q   + (size_t)bh * S_ * HD_;
  const h16* Kh = Kc  + (size_t)bh * S_ * HD_;
  const h16* Vh = Vtc + (size_t)bh * HD_ * S_;

  __shared__ alignas(16) h16 Ks[32 * 72];      // [key][hd], stride 72
  __shared__ alignas(16) h16 Vs[64 * 40];      // [hd][key], stride 40
  __shared__ alignas(16) h16 Pb[4][16 * 40];   // per-wave P, [qrow][key]

  h8 aq[2];
#pragma unroll
  for (int ks = 0; ks < 2; ks++)
    aq[ks] = *(const h8*)(&Qh[(size_t)(q0 + l16) * 64 + ks * 32 + quad * 8]);

  const f32x4 zero = {0.f, 0.f, 0.f, 0.f};
  f32x4 oacc[4];
#pragma unroll
  for (int j = 0; j < 4; j++) oacc[j] = zero;
  float mst[4], lst[4];
#pragma unroll
  for (int r = 0; r < 4; r++) { mst[r] = -1e30f; lst[r] = 0.f; }

  for (int kb = 0; kb < nv; kb += 32) {
    __syncthreads();
    {
      int c = tid;
      int key = c >> 3, ko = (c & 7) * 8;   // 32 keys x 64 hd
      *(uint4*)(&Ks[key * 72 + ko]) =
          *(const uint4*)(&Kh[(size_t)(kb + key) * 64 + ko]);
      int hd = c >> 2, vo = (c & 3) * 8;    // 64 hd x 32 keys
      *(uint4*)(&Vs[hd * 40 + vo]) =
          *(const uint4*)(&Vh[(size_t)hd * S_ + kb + vo]);
    }
    __syncthreads();

    // QK^T: two 16-key halves; tail masked by index (pos >= nv -> -1e30)
    f32x4 st[2];
#pragma unroll
    for (int kh = 0; kh < 2; kh++) {
      h8 bk0 = *(const h8*)(&Ks[(kh * 16 + l16) * 72 + quad * 8]);
      h8 bk1 = *(const h8*)(&Ks[(kh * 16 + l16) * 72 + 32 + quad * 8]);
      f32x4 s = zero;
      s = __builtin_amdgcn_mfma_f32_16x16x32_f16(aq[0], bk0, s, 0, 0, 0);
      s = __builtin_amdgcn_mfma_f32_16x16x32_f16(aq[1], bk1, s, 0, 0, 0);
      if (kb + kh * 16 + l16 >= nv) { s[0] = s[1] = s[2] = s[3] = -1e30f; }
      st[kh] = s;
    }

    // online softmax per q-row
    float p0[4], p1[4], alpha[4];
#pragma unroll
    for (int r = 0; r < 4; r++) {
      float mx = fmaxf(st[0][r], st[1][r]);
#pragma unroll
      for (int o = 1; o < 16; o <<= 1) mx = fmaxf(mx, __shfl_xor(mx, o, 64));
      float mnew = fmaxf(mst[r], mx);
      alpha[r] = __expf(mst[r] - mnew);
      p0[r] = __expf(st[0][r] - mnew);
      p1[r] = __expf(st[1][r] - mnew);
      float rs = p0[r] + p1[r];
#pragma unroll
      for (int o = 1; o < 16; o <<= 1) rs += __shfl_xor(rs, o, 64);
      lst[r] = lst[r] * alpha[r] + rs;
      mst[r] = mnew;
    }
#pragma unroll
    for (int j = 0; j < 4; j++)
#pragma unroll
      for (int r = 0; r < 4; r++) oacc[j][r] *= alpha[r];

    // P: C-layout -> A-layout via per-wave LDS round-trip
    h16* pb = Pb[w];
#pragma unroll
    for (int r = 0; r < 4; r++) {
      pb[(quad * 4 + r) * 40 + l16]      = (h16)p0[r];
      pb[(quad * 4 + r) * 40 + 16 + l16] = (h16)p1[r];
    }
    __syncthreads();
    h8 pa = *(const h8*)(&pb[l16 * 40 + quad * 8]);

    // PV: O(16x64) += P(16x32) * V(32x64)
#pragma unroll
    for (int j = 0; j < 4; j++) {
      h8 bv = *(const h8*)(&Vs[(j * 16 + l16) * 40 + quad * 8]);
      oacc[j] = __builtin_amdgcn_mfma_f32_16x16x32_f16(pa, bv, oacc[j], 0, 0, 0);
    }
  }

  // epilogue
#pragma unroll
  for (int j = 0; j < 4; j++)
#pragma unroll
    for (int r = 0; r < 4; r++) {
      int row = q0 + quad * 4 + r;
      float v = oacc[j][r] / lst[r];
      out[((size_t)(b * S_ + row)) * D_ + h * 64 + j * 16 + l16] = (h16)v;
    }
}

// ---------------------------------------------------------------------------
// ws (64 MiB, fp16 elems): Qb[0,NT) Kc[NT,2NT) Vtc[2NT,3NT)
// R3[3NT,4NT): xc (dead before attn) then AOb. WouT aliases Qb (post-attn);
// boutc aliases Vtc. d_out (33.5 MB) as pre-gemm<1> scratch: WinT, binc,
// posmap (24 MB off), nvalid — all dead before gemm<1> overwrites d_out.
// ---------------------------------------------------------------------------
extern "C" void kernel_launch(void* const* d_in, const int* in_sizes, int n_in,
                              void* d_out, int out_size, void* d_ws,
                              size_t ws_size, hipStream_t stream) {
  const float* x     = (const float*)d_in[0];
  const float* w_in  = (const float*)d_in[1];
  const float* b_in  = (const float*)d_in[2];
  const float* w_out = (const float*)d_in[3];
  const float* b_out = (const float*)d_in[4];
  const int*   mask  = (const int*)d_in[5];

  const size_t NT = (size_t)BH_ * S_ * HD_;    // 8,388,608 elems
  h16* ws    = (h16*)d_ws;
  h16* Qb    = ws;
  h16* Kcb   = ws + NT;
  h16* Vtcb  = ws + 2 * NT;
  h16* xc    = ws + 3 * NT;
  h16* AOb   = ws + 3 * NT;
  h16* WouT  = Qb;
  h16* boutc = Vtcb;
  h16* WinT  = (h16*)d_out;
  h16* binc  = (h16*)d_out + 3400704;
  int* posmap = (int*)((char*)d_out + 24u * 1024 * 1024);
  int* nvalid = posmap + B_ * S_;

  maskscan_k<<<B_, 256, 0, stream>>>(mask, posmap, nvalid);
  convert_k<<<2, 256, 0, stream>>>(b_in, binc, 3 * D_);
  transpose_conv_k<<<dim3(3 * D_ / 32, D_ / 32), dim3(32, 8), 0, stream>>>(
      w_in, WinT, D_, 3 * D_);
  convert_k<<<(B_ * S_ * D_) / 2048, 256, 0, stream>>>(x, xc, B_ * S_ * D_);

  gemm_bt<0><<<dim3((B_ * S_) / 128, (3 * D_) / 128), 256, 0, stream>>>(
      xc, WinT, binc, posmap, Qb, Kcb, Vtcb, B_ * S_, 3 * D_, D_);

  attn_k<<<dim3(S_ / 64, BH_), 256, 0, stream>>>(Qb, Kcb, Vtcb, nvalid, AOb);

  transpose_conv_k<<<dim3(D_ / 32, D_ / 32), dim3(32, 8), 0, stream>>>(
      w_out, WouT, D_, D_);
  convert_k<<<1, 256, 0, stream>>>(b_out, boutc, D_);

  gemm_bt<1><<<dim3((B_ * S_) / 128, D_ / 128), 256, 0, stream>>>(
      AOb, WouT, boutc, nullptr, d_out, nullptr, nullptr, B_ * S_, D_, D_);
}

// Round 6
// 330.359 us; speedup vs baseline: 1.6037x; 1.1898x over previous
//
#include <hip/hip_runtime.h>

// Problem: B=4, S=2048, D=1024, H=16, HD=64. f32 in/out, fp16 MFMA compute,
// fp32 accumulate. Mask-compacted attention + transposed-score softmax.
#define B_  4
#define S_  2048
#define D_  1024
#define H_  16
#define HD_ 64
#define BH_ (B_*H_)

typedef _Float16 h16;
typedef _Float16 h4 __attribute__((ext_vector_type(4)));
typedef _Float16 h8 __attribute__((ext_vector_type(8)));
typedef float    f32x4 __attribute__((ext_vector_type(4)));

// ---------------------------------------------------------------------------
// Per-batch mask prefix-scan: posmap[b][s] = compacted index (or -1),
// nvalid[b] = count. One block per batch, 256 threads x 8 elems.
// ---------------------------------------------------------------------------
__global__ void maskscan_k(const int* __restrict__ mask,
                           int* __restrict__ posmap, int* __restrict__ nvalid) {
  __shared__ int partial[256];
  int b = blockIdx.x;
  const int* mb = mask + b * S_;
  int t = threadIdx.x;
  int base = t * 8;
  int loc[8], cnt = 0;
#pragma unroll
  for (int j = 0; j < 8; j++) { loc[j] = cnt; cnt += (mb[base + j] != 0); }
  partial[t] = cnt;
  __syncthreads();
  for (int off = 1; off < 256; off <<= 1) {
    int v = (t >= off) ? partial[t - off] : 0;
    __syncthreads();
    partial[t] += v;
    __syncthreads();
  }
  int excl = (t == 0) ? 0 : partial[t - 1];
#pragma unroll
  for (int j = 0; j < 8; j++)
    posmap[b * S_ + base + j] = (mb[base + j] != 0) ? (excl + loc[j]) : -1;
  if (t == 255) nvalid[b] = partial[255];
}

// ---------------------------------------------------------------------------
// Convert f32 -> fp16. 8 elems/thread, vectorized.
// ---------------------------------------------------------------------------
__global__ void convert_k(const float* __restrict__ in, h16* __restrict__ out,
                          int n) {
  int idx = (blockIdx.x * 256 + threadIdx.x) * 8;
  if (idx + 8 <= n) {
    float4 f0 = *(const float4*)(in + idx);
    float4 f1 = *(const float4*)(in + idx + 4);
    h16 t[8] = {(h16)f0.x, (h16)f0.y, (h16)f0.z, (h16)f0.w,
                (h16)f1.x, (h16)f1.y, (h16)f1.z, (h16)f1.w};
    *(h8*)(out + idx) = *(h8*)t;
  } else {
    for (int j = idx; j < n; j++) out[j] = (h16)in[j];
  }
}

// ---------------------------------------------------------------------------
// Fused convert + transpose: in (R x C) f32 -> out (C x R) fp16
// ---------------------------------------------------------------------------
__global__ void transpose_conv_k(const float* __restrict__ in,
                                 h16* __restrict__ out, int R, int C) {
  __shared__ h16 tile[32][33];
  int bx = blockIdx.x * 32;
  int by = blockIdx.y * 32;
  int tx = threadIdx.x, ty = threadIdx.y;  // block (32, 8)
#pragma unroll
  for (int i = 0; i < 32; i += 8)
    tile[ty + i][tx] = (h16)in[(size_t)(by + ty + i) * C + bx + tx];
  __syncthreads();
#pragma unroll
  for (int i = 0; i < 32; i += 8)
    out[(size_t)(bx + ty + i) * R + by + tx] = tile[tx][ty + i];
}

// ---------------------------------------------------------------------------
// MFMA GEMM: A (M x K) row-major fp16, BT (N x K) row-major fp16, 128x128x32.
// MODE 0: qkv proj -> Q (scaled,+bias); K,V scattered through posmap into
//         compacted Kc (bh,pos,hd) / Vtc (bh,hd,pos). Invalid keys dropped.
// MODE 1: out projection -> d_out f32 (+bias)
// ---------------------------------------------------------------------------
template <int MODE>
__global__ __launch_bounds__(256)
void gemm_bt(const h16* __restrict__ A, const h16* __restrict__ BT,
             const h16* __restrict__ bias, const int* __restrict__ posmap,
             void* __restrict__ out0v, h16* __restrict__ out1,
             h16* __restrict__ out2, int M, int N, int K) {
  const int tid  = threadIdx.x;
  const int lane = tid & 63;
  const int w    = tid >> 6;
  const int quad = lane >> 4;
  const int l16  = lane & 15;
  const int m0   = blockIdx.x * 128;
  const int n0   = blockIdx.y * 128;

  __shared__ alignas(16) h16 As[128 * 40];  // stride 40 -> 2-way banks (free)
  __shared__ alignas(16) h16 Bs[128 * 40];

  const f32x4 zero = {0.f, 0.f, 0.f, 0.f};
  f32x4 acc[4][4];
#pragma unroll
  for (int i = 0; i < 4; i++)
#pragma unroll
    for (int j = 0; j < 4; j++) acc[i][j] = zero;

  const int wm = (w >> 1) * 64;
  const int wn = (w & 1) * 64;

  for (int kt = 0; kt < K; kt += 32) {
#pragma unroll
    for (int c = 0; c < 2; c++) {
      int idx = tid + c * 256;
      int row = idx >> 2;
      int ko  = (idx & 3) * 8;
      *(uint4*)(&As[row * 40 + ko]) =
          *(const uint4*)(&A[(size_t)(m0 + row) * K + kt + ko]);
      *(uint4*)(&Bs[row * 40 + ko]) =
          *(const uint4*)(&BT[(size_t)(n0 + row) * K + kt + ko]);
    }
    __syncthreads();
    h8 af[4], bfr[4];
#pragma unroll
    for (int i = 0; i < 4; i++)
      af[i] = *(const h8*)(&As[(wm + i * 16 + l16) * 40 + quad * 8]);
#pragma unroll
    for (int j = 0; j < 4; j++)
      bfr[j] = *(const h8*)(&Bs[(wn + j * 16 + l16) * 40 + quad * 8]);
#pragma unroll
    for (int i = 0; i < 4; i++)
#pragma unroll
      for (int j = 0; j < 4; j++)
        acc[i][j] = __builtin_amdgcn_mfma_f32_16x16x32_f16(af[i], bfr[j],
                                                           acc[i][j], 0, 0, 0);
    __syncthreads();
  }

  // epilogue
#pragma unroll
  for (int i = 0; i < 4; i++) {
#pragma unroll
    for (int j = 0; j < 4; j++) {
      int n = n0 + wn + j * 16 + l16;
      float bv = (float)bias[n];
#pragma unroll
      for (int r = 0; r < 4; r++) {
        int m = m0 + wm + i * 16 + quad * 4 + r;
        float v = acc[i][j][r] + bv;
        if (MODE == 0) {
          h16* q0 = (h16*)out0v;
          int which = n >> 10;          // 0=Q, 1=K, 2=V
          int h  = (n >> 6) & 15;
          int hd = n & 63;
          int b  = m >> 11;             // S_=2048
          int s  = m & 2047;
          if (which == 0) {
            q0[(((size_t)(b * 16 + h)) * S_ + s) * HD_ + hd] = (h16)(v * 0.125f);
          } else {
            int pos = posmap[b * S_ + s];
            if (pos >= 0) {
              if (which == 1)  // compacted K: (bh, pos, hd)
                out1[(((size_t)(b * 16 + h)) * S_ + pos) * HD_ + hd] = (h16)v;
              else             // compacted V^T: (bh, hd, pos)
                out2[(((size_t)(b * 16 + h)) * HD_ + hd) * S_ + pos] = (h16)v;
            }
          }
        } else {
          ((float*)out0v)[(size_t)m * N + n] = v;   // f32 output
        }
      }
    }
  }
}

// ---------------------------------------------------------------------------
// Flash attention, transposed scores: grid (S/64, B*H), block 256
// (4 waves x 16 q-rows). QK^T computed as S^T = K*Q^T (K as A-operand):
// col=q (l16), row=key (quad*4+reg). Softmax per q is then IN-LANE over 8
// scores + 2 cross-quad shuffles (vs 32 shuffles row-mapped). P^T written
// to per-wave LDS [q][key] = PV A-layout directly (packed b64 stores).
// ---------------------------------------------------------------------------
__global__ __launch_bounds__(256)
void attn_k(const h16* __restrict__ Q, const h16* __restrict__ Kc,
            const h16* __restrict__ Vtc, const int* __restrict__ nvalid,
            h16* __restrict__ out) {
  const int tid  = threadIdx.x;
  const int lane = tid & 63;
  const int w    = tid >> 6;
  const int quad = lane >> 4;
  const int l16  = lane & 15;
  const int bh   = blockIdx.y;
  const int b    = bh >> 4, h = bh & 15;
  const int q0   = blockIdx.x * 64 + w * 16;
  const int nv   = nvalid[b];

  const h16* Qh = Q   + (size_t)bh * S_ * HD_;
  const h16* Kh = Kc  + (size_t)bh * S_ * HD_;
  const h16* Vh = Vtc + (size_t)bh * HD_ * S_;

  __shared__ alignas(16) h16 Ks[32 * 72];      // [key][hd], stride 72
  __shared__ alignas(16) h16 Vs[64 * 40];      // [hd][key], stride 40
  __shared__ alignas(16) h16 Pb[4][16 * 40];   // per-wave P, [q][key]

  // Q fragment, used as MFMA B-operand (n=q, k=hd)
  h8 bq[2];
#pragma unroll
  for (int ks = 0; ks < 2; ks++)
    bq[ks] = *(const h8*)(&Qh[(size_t)(q0 + l16) * 64 + ks * 32 + quad * 8]);

  const f32x4 zero = {0.f, 0.f, 0.f, 0.f};
  f32x4 oacc[4];
#pragma unroll
  for (int j = 0; j < 4; j++) oacc[j] = zero;
  float mst = -1e30f, lst = 0.f;   // per-lane state for q = q0 + l16

  for (int kb = 0; kb < nv; kb += 32) {
    __syncthreads();
    {
      int c = tid;
      int key = c >> 3, ko = (c & 7) * 8;   // 32 keys x 64 hd
      *(uint4*)(&Ks[key * 72 + ko]) =
          *(const uint4*)(&Kh[(size_t)(kb + key) * 64 + ko]);
      int hd = c >> 2, vo = (c & 3) * 8;    // 64 hd x 32 keys
      *(uint4*)(&Vs[hd * 40 + vo]) =
          *(const uint4*)(&Vh[(size_t)hd * S_ + kb + vo]);
    }
    __syncthreads();

    // S^T: st[kh][r] = S[key = kh*16 + quad*4 + r][q = q0 + l16]
    f32x4 st[2];
#pragma unroll
    for (int kh = 0; kh < 2; kh++) {
      h8 ak0 = *(const h8*)(&Ks[(kh * 16 + l16) * 72 + quad * 8]);
      h8 ak1 = *(const h8*)(&Ks[(kh * 16 + l16) * 72 + 32 + quad * 8]);
      f32x4 s = zero;
      s = __builtin_amdgcn_mfma_f32_16x16x32_f16(ak0, bq[0], s, 0, 0, 0);
      s = __builtin_amdgcn_mfma_f32_16x16x32_f16(ak1, bq[1], s, 0, 0, 0);
      st[kh] = s;
    }
    if (kb + 32 > nv) {  // wave-uniform: only the last block pays this
#pragma unroll
      for (int kh = 0; kh < 2; kh++)
#pragma unroll
        for (int r = 0; r < 4; r++)
          if (kb + kh * 16 + quad * 4 + r >= nv) st[kh][r] = -1e30f;
    }

    // in-lane max over 8 scores, then 2 cross-quad shuffles
    float mx = fmaxf(fmaxf(fmaxf(st[0][0], st[0][1]), fmaxf(st[0][2], st[0][3])),
                     fmaxf(fmaxf(st[1][0], st[1][1]), fmaxf(st[1][2], st[1][3])));
    mx = fmaxf(mx, __shfl_xor(mx, 16, 64));
    mx = fmaxf(mx, __shfl_xor(mx, 32, 64));
    float mnew = fmaxf(mst, mx);
    float alpha = __expf(mst - mnew);
    float p[2][4], rs = 0.f;
#pragma unroll
    for (int kh = 0; kh < 2; kh++)
#pragma unroll
      for (int r = 0; r < 4; r++) {
        p[kh][r] = __expf(st[kh][r] - mnew);
        rs += p[kh][r];
      }
    rs += __shfl_xor(rs, 16, 64);
    rs += __shfl_xor(rs, 32, 64);
    lst = lst * alpha + rs;
    mst = mnew;

    // broadcast alpha into O's row mapping (q = quad*4 + r lives in lane q)
    float al[4];
#pragma unroll
    for (int r = 0; r < 4; r++) al[r] = __shfl(alpha, quad * 4 + r, 64);
#pragma unroll
    for (int j = 0; j < 4; j++)
#pragma unroll
      for (int r = 0; r < 4; r++) oacc[j][r] *= al[r];

    // P^T -> per-wave LDS [q][key]: already the PV A-layout. Packed b64.
    h16* pb = Pb[w];
#pragma unroll
    for (int kh = 0; kh < 2; kh++) {
      h4 pk = {(h16)p[kh][0], (h16)p[kh][1], (h16)p[kh][2], (h16)p[kh][3]};
      *(h4*)(&pb[l16 * 40 + kh * 16 + quad * 4]) = pk;
    }
    // same-wave LDS RAW: compiler-ordered (aliasing array), no barrier needed
    h8 pa = *(const h8*)(&pb[l16 * 40 + quad * 8]);

    // PV: O(16q x 64hd) += P(16q x 32k) * V(32k x 64hd)
#pragma unroll
    for (int j = 0; j < 4; j++) {
      h8 bv = *(const h8*)(&Vs[(j * 16 + l16) * 40 + quad * 8]);
      oacc[j] = __builtin_amdgcn_mfma_f32_16x16x32_f16(pa, bv, oacc[j], 0, 0, 0);
    }
  }

  // epilogue: q = q0 + quad*4 + r, hd = h*64 + j*16 + l16; l via shuffle
  float ls[4];
#pragma unroll
  for (int r = 0; r < 4; r++) ls[r] = __shfl(lst, quad * 4 + r, 64);
#pragma unroll
  for (int j = 0; j < 4; j++)
#pragma unroll
    for (int r = 0; r < 4; r++) {
      int row = q0 + quad * 4 + r;
      float v = oacc[j][r] / ls[r];
      out[((size_t)(b * S_ + row)) * D_ + h * 64 + j * 16 + l16] = (h16)v;
    }
}

// ---------------------------------------------------------------------------
// ws (64 MiB, fp16 elems): Qb[0,NT) Kc[NT,2NT) Vtc[2NT,3NT)
// R3[3NT,4NT): xc (dead before attn) then AOb. WouT aliases Qb (post-attn);
// boutc aliases Vtc. d_out (33.5 MB) as pre-gemm<1> scratch: WinT, binc,
// posmap (24 MB off), nvalid — all dead before gemm<1> overwrites d_out.
// ---------------------------------------------------------------------------
extern "C" void kernel_launch(void* const* d_in, const int* in_sizes, int n_in,
                              void* d_out, int out_size, void* d_ws,
                              size_t ws_size, hipStream_t stream) {
  const float* x     = (const float*)d_in[0];
  const float* w_in  = (const float*)d_in[1];
  const float* b_in  = (const float*)d_in[2];
  const float* w_out = (const float*)d_in[3];
  const float* b_out = (const float*)d_in[4];
  const int*   mask  = (const int*)d_in[5];

  const size_t NT = (size_t)BH_ * S_ * HD_;    // 8,388,608 elems
  h16* ws    = (h16*)d_ws;
  h16* Qb    = ws;
  h16* Kcb   = ws + NT;
  h16* Vtcb  = ws + 2 * NT;
  h16* xc    = ws + 3 * NT;
  h16* AOb   = ws + 3 * NT;
  h16* WouT  = Qb;
  h16* boutc = Vtcb;
  h16* WinT  = (h16*)d_out;
  h16* binc  = (h16*)d_out + 3400704;
  int* posmap = (int*)((char*)d_out + 24u * 1024 * 1024);
  int* nvalid = posmap + B_ * S_;

  maskscan_k<<<B_, 256, 0, stream>>>(mask, posmap, nvalid);
  convert_k<<<2, 256, 0, stream>>>(b_in, binc, 3 * D_);
  transpose_conv_k<<<dim3(3 * D_ / 32, D_ / 32), dim3(32, 8), 0, stream>>>(
      w_in, WinT, D_, 3 * D_);
  convert_k<<<(B_ * S_ * D_) / 2048, 256, 0, stream>>>(x, xc, B_ * S_ * D_);

  gemm_bt<0><<<dim3((B_ * S_) / 128, (3 * D_) / 128), 256, 0, stream>>>(
      xc, WinT, binc, posmap, Qb, Kcb, Vtcb, B_ * S_, 3 * D_, D_);

  attn_k<<<dim3(S_ / 64, BH_), 256, 0, stream>>>(Qb, Kcb, Vtcb, nvalid, AOb);

  transpose_conv_k<<<dim3(D_ / 32, D_ / 32), dim3(32, 8), 0, stream>>>(
      w_out, WouT, D_, D_);
  convert_k<<<1, 256, 0, stream>>>(b_out, boutc, D_);

  gemm_bt<1><<<dim3((B_ * S_) / 128, D_ / 128), 256, 0, stream>>>(
      AOb, WouT, boutc, nullptr, d_out, nullptr, nullptr, B_ * S_, D_, D_);
}

// Round 7
// 312.985 us; speedup vs baseline: 1.6927x; 1.0555x over previous
//
#include <hip/hip_runtime.h>

// Problem: B=4, S=2048, D=1024, H=16, HD=64. f32 in/out, fp16 MFMA compute,
// fp32 accumulate. Mask-compacted attention + transposed-score softmax.
// R7: m97-style global_load_lds GEMM staging; 64-key attention tiles.
#define B_  4
#define S_  2048
#define D_  1024
#define H_  16
#define HD_ 64
#define BH_ (B_*H_)

typedef _Float16 h16;
typedef _Float16 h4 __attribute__((ext_vector_type(4)));
typedef _Float16 h8 __attribute__((ext_vector_type(8)));
typedef float    f32x4 __attribute__((ext_vector_type(4)));

// async global->LDS, 16B per lane. ldst is wave-uniform base; HW scatters
// lane i's 16B to ldst + i*16 (m97/m104: no per-lane LDS scatter).
__device__ __forceinline__ void gload16(const h16* g, h16* l) {
  __builtin_amdgcn_global_load_lds(
      (const __attribute__((address_space(1))) unsigned int*)g,
      (__attribute__((address_space(3))) unsigned int*)l, 16, 0, 0);
}

// ---------------------------------------------------------------------------
// Per-batch mask prefix-scan: posmap[b][s] = compacted index (or -1),
// nvalid[b] = count. One block per batch, 256 threads x 8 elems.
// ---------------------------------------------------------------------------
__global__ void maskscan_k(const int* __restrict__ mask,
                           int* __restrict__ posmap, int* __restrict__ nvalid) {
  __shared__ int partial[256];
  int b = blockIdx.x;
  const int* mb = mask + b * S_;
  int t = threadIdx.x;
  int base = t * 8;
  int loc[8], cnt = 0;
#pragma unroll
  for (int j = 0; j < 8; j++) { loc[j] = cnt; cnt += (mb[base + j] != 0); }
  partial[t] = cnt;
  __syncthreads();
  for (int off = 1; off < 256; off <<= 1) {
    int v = (t >= off) ? partial[t - off] : 0;
    __syncthreads();
    partial[t] += v;
    __syncthreads();
  }
  int excl = (t == 0) ? 0 : partial[t - 1];
#pragma unroll
  for (int j = 0; j < 8; j++)
    posmap[b * S_ + base + j] = (mb[base + j] != 0) ? (excl + loc[j]) : -1;
  if (t == 255) nvalid[b] = partial[255];
}

// ---------------------------------------------------------------------------
// Convert f32 -> fp16. 8 elems/thread, vectorized.
// ---------------------------------------------------------------------------
__global__ void convert_k(const float* __restrict__ in, h16* __restrict__ out,
                          int n) {
  int idx = (blockIdx.x * 256 + threadIdx.x) * 8;
  if (idx + 8 <= n) {
    float4 f0 = *(const float4*)(in + idx);
    float4 f1 = *(const float4*)(in + idx + 4);
    h16 t[8] = {(h16)f0.x, (h16)f0.y, (h16)f0.z, (h16)f0.w,
                (h16)f1.x, (h16)f1.y, (h16)f1.z, (h16)f1.w};
    *(h8*)(out + idx) = *(h8*)t;
  } else {
    for (int j = idx; j < n; j++) out[j] = (h16)in[j];
  }
}

// ---------------------------------------------------------------------------
// Fused convert + transpose: in (R x C) f32 -> out (C x R) fp16
// ---------------------------------------------------------------------------
__global__ void transpose_conv_k(const float* __restrict__ in,
                                 h16* __restrict__ out, int R, int C) {
  __shared__ h16 tile[32][33];
  int bx = blockIdx.x * 32;
  int by = blockIdx.y * 32;
  int tx = threadIdx.x, ty = threadIdx.y;  // block (32, 8)
#pragma unroll
  for (int i = 0; i < 32; i += 8)
    tile[ty + i][tx] = (h16)in[(size_t)(by + ty + i) * C + bx + tx];
  __syncthreads();
#pragma unroll
  for (int i = 0; i < 32; i += 8)
    out[(size_t)(bx + ty + i) * R + by + tx] = tile[tx][ty + i];
}

// ---------------------------------------------------------------------------
// MFMA GEMM (m97 structure): A (M x K) rm fp16, BT (N x K) rm fp16,
// 128x128x32 tiles, global_load_lds width-16 staging, unpadded LDS.
// MODE 0: qkv proj -> Q (scaled,+bias); K,V scattered through posmap.
// MODE 1: out projection -> d_out f32 (+bias)
// ---------------------------------------------------------------------------
template <int MODE>
__global__ __launch_bounds__(256)
void gemm_bt(const h16* __restrict__ A, const h16* __restrict__ BT,
             const h16* __restrict__ bias, const int* __restrict__ posmap,
             void* __restrict__ out0v, h16* __restrict__ out1,
             h16* __restrict__ out2, int M, int N, int K) {
  const int tid  = threadIdx.x;
  const int lane = tid & 63;
  const int w    = tid >> 6;
  const int quad = lane >> 4;
  const int l16  = lane & 15;
  const int m0   = blockIdx.x * 128;
  const int n0   = blockIdx.y * 128;

  __shared__ alignas(16) h16 As[128 * 32];  // unpadded: global_load_lds dest
  __shared__ alignas(16) h16 Bs[128 * 32];

  const f32x4 zero = {0.f, 0.f, 0.f, 0.f};
  f32x4 acc[4][4];
#pragma unroll
  for (int i = 0; i < 4; i++)
#pragma unroll
    for (int j = 0; j < 4; j++) acc[i][j] = zero;

  const int wm = (w >> 1) * 64;
  const int wn = (w & 1) * 64;
  const int srow = (lane >> 2);        // 0..15 within chunk
  const int sko  = (lane & 3) * 8;     // 16B column offset

  for (int kt = 0; kt < K; kt += 32) {
#pragma unroll
    for (int c = 0; c < 2; c++) {
      int chunk = w * 2 + c;           // 0..7: 16 rows each
      int row = chunk * 16 + srow;
      gload16(&A[(size_t)(m0 + row) * K + kt + sko], &As[chunk * 512]);
      gload16(&BT[(size_t)(n0 + row) * K + kt + sko], &Bs[chunk * 512]);
    }
    __syncthreads();
    h8 af[4], bfr[4];
#pragma unroll
    for (int i = 0; i < 4; i++)
      af[i] = *(const h8*)(&As[(wm + i * 16 + l16) * 32 + quad * 8]);
#pragma unroll
    for (int j = 0; j < 4; j++)
      bfr[j] = *(const h8*)(&Bs[(wn + j * 16 + l16) * 32 + quad * 8]);
#pragma unroll
    for (int i = 0; i < 4; i++)
#pragma unroll
      for (int j = 0; j < 4; j++)
        acc[i][j] = __builtin_amdgcn_mfma_f32_16x16x32_f16(af[i], bfr[j],
                                                           acc[i][j], 0, 0, 0);
    __syncthreads();
  }

  // epilogue
#pragma unroll
  for (int i = 0; i < 4; i++) {
#pragma unroll
    for (int j = 0; j < 4; j++) {
      int n = n0 + wn + j * 16 + l16;
      float bv = (float)bias[n];
#pragma unroll
      for (int r = 0; r < 4; r++) {
        int m = m0 + wm + i * 16 + quad * 4 + r;
        float v = acc[i][j][r] + bv;
        if (MODE == 0) {
          h16* q0 = (h16*)out0v;
          int which = n >> 10;          // 0=Q, 1=K, 2=V
          int h  = (n >> 6) & 15;
          int hd = n & 63;
          int b  = m >> 11;             // S_=2048
          int s  = m & 2047;
          if (which == 0) {
            q0[(((size_t)(b * 16 + h)) * S_ + s) * HD_ + hd] = (h16)(v * 0.125f);
          } else {
            int pos = posmap[b * S_ + s];
            if (pos >= 0) {
              if (which == 1)  // compacted K: (bh, pos, hd)
                out1[(((size_t)(b * 16 + h)) * S_ + pos) * HD_ + hd] = (h16)v;
              else             // compacted V^T: (bh, hd, pos)
                out2[(((size_t)(b * 16 + h)) * HD_ + hd) * S_ + pos] = (h16)v;
            }
          }
        } else {
          ((float*)out0v)[(size_t)m * N + n] = v;   // f32 output
        }
      }
    }
  }
}

// ---------------------------------------------------------------------------
// Flash attention, transposed scores, 64-key tiles: grid (S/64, B*H),
// block 256 (4 waves x 16 q-rows). S^T = K*Q^T (K as A-operand): col=q(l16),
// row=key(quad*4+reg). Per-q softmax in-lane over 16 scores + 2 shuffles.
// P^T in per-wave LDS [q][key] = PV A-layout directly.
// ---------------------------------------------------------------------------
__global__ __launch_bounds__(256)
void attn_k(const h16* __restrict__ Q, const h16* __restrict__ Kc,
            const h16* __restrict__ Vtc, const int* __restrict__ nvalid,
            h16* __restrict__ out) {
  const int tid  = threadIdx.x;
  const int lane = tid & 63;
  const int w    = tid >> 6;
  const int quad = lane >> 4;
  const int l16  = lane & 15;
  const int bh   = blockIdx.y;
  const int b    = bh >> 4, h = bh & 15;
  const int q0   = blockIdx.x * 64 + w * 16;
  const int nv   = nvalid[b];

  const h16* Qh = Q   + (size_t)bh * S_ * HD_;
  const h16* Kh = Kc  + (size_t)bh * S_ * HD_;
  const h16* Vh = Vtc + (size_t)bh * HD_ * S_;

  __shared__ alignas(16) h16 Ks[64 * 72];      // [key][hd], stride 72
  __shared__ alignas(16) h16 Vs[64 * 72];      // [hd][key], stride 72
  __shared__ alignas(16) h16 Pb[4][16 * 72];   // per-wave P^T, [q][key]

  // Q fragment, used as MFMA B-operand (n=q, k=hd)
  h8 bq[2];
#pragma unroll
  for (int ks = 0; ks < 2; ks++)
    bq[ks] = *(const h8*)(&Qh[(size_t)(q0 + l16) * 64 + ks * 32 + quad * 8]);

  const f32x4 zero = {0.f, 0.f, 0.f, 0.f};
  f32x4 oacc[4];
#pragma unroll
  for (int j = 0; j < 4; j++) oacc[j] = zero;
  float mst = -1e30f, lst = 0.f;   // per-lane state for q = q0 + l16

  for (int kb = 0; kb < nv; kb += 64) {
    __syncthreads();
#pragma unroll
    for (int pass = 0; pass < 2; pass++) {
      int c = tid + pass * 256;
      int key = c >> 3, ko = (c & 7) * 8;   // 64 keys x 64 hd
      *(uint4*)(&Ks[key * 72 + ko]) =
          *(const uint4*)(&Kh[(size_t)(kb + key) * 64 + ko]);
      int hd = c >> 3, vo = (c & 7) * 8;    // 64 hd x 64 keys
      *(uint4*)(&Vs[hd * 72 + vo]) =
          *(const uint4*)(&Vh[(size_t)hd * S_ + kb + vo]);
    }
    __syncthreads();

    // S^T: st[kh][r] = S[key = kh*16 + quad*4 + r][q = q0 + l16]
    f32x4 st[4];
#pragma unroll
    for (int kh = 0; kh < 4; kh++) {
      h8 ak0 = *(const h8*)(&Ks[(kh * 16 + l16) * 72 + quad * 8]);
      h8 ak1 = *(const h8*)(&Ks[(kh * 16 + l16) * 72 + 32 + quad * 8]);
      f32x4 s = zero;
      s = __builtin_amdgcn_mfma_f32_16x16x32_f16(ak0, bq[0], s, 0, 0, 0);
      s = __builtin_amdgcn_mfma_f32_16x16x32_f16(ak1, bq[1], s, 0, 0, 0);
      st[kh] = s;
    }
    if (kb + 64 > nv) {  // wave-uniform: only the last block pays this
#pragma unroll
      for (int kh = 0; kh < 4; kh++)
#pragma unroll
        for (int r = 0; r < 4; r++)
          if (kb + kh * 16 + quad * 4 + r >= nv) st[kh][r] = -1e30f;
    }

    // in-lane max over 16 scores, then 2 cross-quad shuffles
    float mx = -1e30f;
#pragma unroll
    for (int kh = 0; kh < 4; kh++)
#pragma unroll
      for (int r = 0; r < 4; r++) mx = fmaxf(mx, st[kh][r]);
    mx = fmaxf(mx, __shfl_xor(mx, 16, 64));
    mx = fmaxf(mx, __shfl_xor(mx, 32, 64));
    float mnew = fmaxf(mst, mx);
    float alpha = __expf(mst - mnew);
    float p[4][4], rs = 0.f;
#pragma unroll
    for (int kh = 0; kh < 4; kh++)
#pragma unroll
      for (int r = 0; r < 4; r++) {
        p[kh][r] = __expf(st[kh][r] - mnew);
        rs += p[kh][r];
      }
    rs += __shfl_xor(rs, 16, 64);
    rs += __shfl_xor(rs, 32, 64);
    lst = lst * alpha + rs;
    mst = mnew;

    // broadcast alpha into O's row mapping (q = quad*4 + r lives in lane q)
    float al[4];
#pragma unroll
    for (int r = 0; r < 4; r++) al[r] = __shfl(alpha, quad * 4 + r, 64);
#pragma unroll
    for (int j = 0; j < 4; j++)
#pragma unroll
      for (int r = 0; r < 4; r++) oacc[j][r] *= al[r];

    // P^T -> per-wave LDS [q][key]: PV A-layout. Packed b64 stores.
    h16* pb = Pb[w];
#pragma unroll
    for (int kh = 0; kh < 4; kh++) {
      h4 pk = {(h16)p[kh][0], (h16)p[kh][1], (h16)p[kh][2], (h16)p[kh][3]};
      *(h4*)(&pb[l16 * 72 + kh * 16 + quad * 4]) = pk;
    }
    // same-wave LDS RAW: in-order LDS pipe per wave (R6-verified), no barrier
    h8 pa0 = *(const h8*)(&pb[l16 * 72 + quad * 8]);
    h8 pa1 = *(const h8*)(&pb[l16 * 72 + 32 + quad * 8]);

    // PV: O(16q x 64hd) += P(16q x 64k) * V(64k x 64hd)
#pragma unroll
    for (int j = 0; j < 4; j++) {
      h8 bv0 = *(const h8*)(&Vs[(j * 16 + l16) * 72 + quad * 8]);
      h8 bv1 = *(const h8*)(&Vs[(j * 16 + l16) * 72 + 32 + quad * 8]);
      oacc[j] = __builtin_amdgcn_mfma_f32_16x16x32_f16(pa0, bv0, oacc[j], 0, 0, 0);
      oacc[j] = __builtin_amdgcn_mfma_f32_16x16x32_f16(pa1, bv1, oacc[j], 0, 0, 0);
    }
  }

  // epilogue: q = q0 + quad*4 + r, hd = h*64 + j*16 + l16; l via shuffle
  float ls[4];
#pragma unroll
  for (int r = 0; r < 4; r++) ls[r] = __shfl(lst, quad * 4 + r, 64);
#pragma unroll
  for (int j = 0; j < 4; j++)
#pragma unroll
    for (int r = 0; r < 4; r++) {
      int row = q0 + quad * 4 + r;
      float v = oacc[j][r] / ls[r];
      out[((size_t)(b * S_ + row)) * D_ + h * 64 + j * 16 + l16] = (h16)v;
    }
}

// ---------------------------------------------------------------------------
// ws (64 MiB, fp16 elems): Qb[0,NT) Kc[NT,2NT) Vtc[2NT,3NT)
// R3[3NT,4NT): xc (dead before attn) then AOb. WouT aliases Qb (post-attn);
// boutc aliases Vtc. d_out (33.5 MB) as pre-gemm<1> scratch: WinT, binc,
// posmap (24 MB off), nvalid — all dead before gemm<1> overwrites d_out.
// ---------------------------------------------------------------------------
extern "C" void kernel_launch(void* const* d_in, const int* in_sizes, int n_in,
                              void* d_out, int out_size, void* d_ws,
                              size_t ws_size, hipStream_t stream) {
  const float* x     = (const float*)d_in[0];
  const float* w_in  = (const float*)d_in[1];
  const float* b_in  = (const float*)d_in[2];
  const float* w_out = (const float*)d_in[3];
  const float* b_out = (const float*)d_in[4];
  const int*   mask  = (const int*)d_in[5];

  const size_t NT = (size_t)BH_ * S_ * HD_;    // 8,388,608 elems
  h16* ws    = (h16*)d_ws;
  h16* Qb    = ws;
  h16* Kcb   = ws + NT;
  h16* Vtcb  = ws + 2 * NT;
  h16* xc    = ws + 3 * NT;
  h16* AOb   = ws + 3 * NT;
  h16* WouT  = Qb;
  h16* boutc = Vtcb;
  h16* WinT  = (h16*)d_out;
  h16* binc  = (h16*)d_out + 3400704;
  int* posmap = (int*)((char*)d_out + 24u * 1024 * 1024);
  int* nvalid = posmap + B_ * S_;

  maskscan_k<<<B_, 256, 0, stream>>>(mask, posmap, nvalid);
  convert_k<<<2, 256, 0, stream>>>(b_in, binc, 3 * D_);
  transpose_conv_k<<<dim3(3 * D_ / 32, D_ / 32), dim3(32, 8), 0, stream>>>(
      w_in, WinT, D_, 3 * D_);
  convert_k<<<(B_ * S_ * D_) / 2048, 256, 0, stream>>>(x, xc, B_ * S_ * D_);

  gemm_bt<0><<<dim3((B_ * S_) / 128, (3 * D_) / 128), 256, 0, stream>>>(
      xc, WinT, binc, posmap, Qb, Kcb, Vtcb, B_ * S_, 3 * D_, D_);

  attn_k<<<dim3(S_ / 64, BH_), 256, 0, stream>>>(Qb, Kcb, Vtcb, nvalid, AOb);

  transpose_conv_k<<<dim3(D_ / 32, D_ / 32), dim3(32, 8), 0, stream>>>(
      w_out, WouT, D_, D_);
  convert_k<<<1, 256, 0, stream>>>(b_out, boutc, D_);

  gemm_bt<1><<<dim3((B_ * S_) / 128, D_ / 128), 256, 0, stream>>>(
      AOb, WouT, boutc, nullptr, d_out, nullptr, nullptr, B_ * S_, D_, D_);
}

// Round 9
// 298.608 us; speedup vs baseline: 1.7742x; 1.0481x over previous
//
#include <hip/hip_runtime.h>

// B=4, S=2048, D=1024, H=16, HD=64. f32 in/out, fp16 MFMA, fp32 accumulate.
// R9 = R8 with __exp2f -> __builtin_amdgcn_exp2f (glibc macro collision fix).
// BK=64 swizzled-glds GEMMs; glds attention staging; exp2 softmax;
// fused prep/post launches (5 kernels total).
#define B_  4
#define S_  2048
#define D_  1024
#define H_  16
#define HD_ 64
#define BH_ (B_*H_)
// Q pre-scale: 1/sqrt(64) * log2(e)  (softmax done in exp2 space)
#define QSCALE 0.18033688f

typedef _Float16 h16;
typedef _Float16 h4 __attribute__((ext_vector_type(4)));
typedef _Float16 h8 __attribute__((ext_vector_type(8)));
typedef float    f32x4 __attribute__((ext_vector_type(4)));

#define EXP2(x) __builtin_amdgcn_exp2f(x)   // v_exp_f32 (D = 2^S0)

// async global->LDS, 16B/lane: lane i's 16B lands at ldst + i*16 (wave-
// uniform base). Swizzled staging: lane reads global chunk (row, cc^(row&7))
// so that LDS chunk (row, cc') holds global (row, cc'^(row&7)).
__device__ __forceinline__ void gload16(const h16* g, h16* l) {
  __builtin_amdgcn_global_load_lds(
      (const __attribute__((address_space(1))) unsigned int*)g,
      (__attribute__((address_space(3))) unsigned int*)l, 16, 0, 0);
}

// ---------------------------------------------------------------------------
// prep: [0,4) maskscan | [4,6) b_in conv | [6,4102) x conv | [4102,7174) w_in T
// ---------------------------------------------------------------------------
__global__ __launch_bounds__(256)
void prep_k(const float* __restrict__ x, const float* __restrict__ w_in,
            const float* __restrict__ b_in, const int* __restrict__ mask,
            h16* __restrict__ xc, h16* __restrict__ WinT,
            h16* __restrict__ binc, int* __restrict__ posmap,
            int* __restrict__ nvalid) {
  __shared__ __align__(16) char smem[2212];
  int blk = blockIdx.x;
  int t = threadIdx.x;
  if (blk < 4) {                      // mask prefix-scan, one block per batch
    int* partial = (int*)smem;
    int b = blk;
    const int* mb = mask + b * S_;
    int base = t * 8;
    int loc[8], cnt = 0;
#pragma unroll
    for (int j = 0; j < 8; j++) { loc[j] = cnt; cnt += (mb[base + j] != 0); }
    partial[t] = cnt;
    __syncthreads();
    for (int off = 1; off < 256; off <<= 1) {
      int v = (t >= off) ? partial[t - off] : 0;
      __syncthreads();
      partial[t] += v;
      __syncthreads();
    }
    int excl = (t == 0) ? 0 : partial[t - 1];
#pragma unroll
    for (int j = 0; j < 8; j++)
      posmap[b * S_ + base + j] = (mb[base + j] != 0) ? (excl + loc[j]) : -1;
    if (t == 255) nvalid[b] = partial[255];
  } else if (blk < 6) {               // b_in convert (3072 elems)
    int idx = ((blk - 4) * 256 + t) * 8;
    if (idx + 8 <= 3 * D_) {
      float4 f0 = *(const float4*)(b_in + idx);
      float4 f1 = *(const float4*)(b_in + idx + 4);
      h16 tmp[8] = {(h16)f0.x, (h16)f0.y, (h16)f0.z, (h16)f0.w,
                    (h16)f1.x, (h16)f1.y, (h16)f1.z, (h16)f1.w};
      *(h8*)(binc + idx) = *(h8*)tmp;
    }
  } else if (blk < 4102) {            // x convert (8.4M elems)
    int idx = ((blk - 6) * 256 + t) * 8;
    float4 f0 = *(const float4*)(x + idx);
    float4 f1 = *(const float4*)(x + idx + 4);
    h16 tmp[8] = {(h16)f0.x, (h16)f0.y, (h16)f0.z, (h16)f0.w,
                  (h16)f1.x, (h16)f1.y, (h16)f1.z, (h16)f1.w};
    *(h8*)(xc + idx) = *(h8*)tmp;
  } else {                            // w_in transpose (1024 x 3072 -> T)
    typedef h16 row33[33];
    row33* tile = (row33*)smem;
    int idx = blk - 4102;             // 96 x 32 tiles
    int bx = (idx % 96) * 32, by = (idx / 96) * 32;
    int tx = t & 31, ty = t >> 5;     // (32, 8)
    const int C = 3 * D_, R = D_;
#pragma unroll
    for (int i = 0; i < 32; i += 8)
      tile[ty + i][tx] = (h16)w_in[(size_t)(by + ty + i) * C + bx + tx];
    __syncthreads();
#pragma unroll
    for (int i = 0; i < 32; i += 8)
      WinT[(size_t)(bx + ty + i) * R + by + tx] = tile[tx][ty + i];
  }
}

// ---------------------------------------------------------------------------
// post: [0,1024) w_out transpose | [1024] b_out convert
// ---------------------------------------------------------------------------
__global__ __launch_bounds__(256)
void post_k(const float* __restrict__ w_out, const float* __restrict__ b_out,
            h16* __restrict__ WouT, h16* __restrict__ boutc) {
  __shared__ h16 tile[32][33];
  int blk = blockIdx.x;
  int t = threadIdx.x;
  if (blk < 1024) {                   // 32 x 32 tiles of (1024,1024)
    int bx = (blk % 32) * 32, by = (blk / 32) * 32;
    int tx = t & 31, ty = t >> 5;
#pragma unroll
    for (int i = 0; i < 32; i += 8)
      tile[ty + i][tx] = (h16)w_out[(size_t)(by + ty + i) * D_ + bx + tx];
    __syncthreads();
#pragma unroll
    for (int i = 0; i < 32; i += 8)
      WouT[(size_t)(bx + ty + i) * D_ + by + tx] = tile[tx][ty + i];
  } else {
    int idx = t * 4;
    if (idx < D_) {
      float4 f = *(const float4*)(b_out + idx);
      h16 tmp[4] = {(h16)f.x, (h16)f.y, (h16)f.z, (h16)f.w};
      *(h4*)(boutc + idx) = *(h4*)tmp;
    }
  }
}

// ---------------------------------------------------------------------------
// MFMA GEMM, BK=64, swizzled glds staging. A (M x K) rm, BT (N x K) rm.
// MODE 0: qkv -> Q (QSCALE,+bias) / compacted Kc,Vtc via posmap.
// MODE 1: out proj -> d_out f32 (+bias).
// ---------------------------------------------------------------------------
template <int MODE>
__global__ __launch_bounds__(256)
void gemm_bt(const h16* __restrict__ A, const h16* __restrict__ BT,
             const h16* __restrict__ bias, const int* __restrict__ posmap,
             void* __restrict__ out0v, h16* __restrict__ out1,
             h16* __restrict__ out2, int M, int N, int K) {
  const int tid  = threadIdx.x;
  const int lane = tid & 63;
  const int w    = tid >> 6;
  const int quad = lane >> 4;
  const int l16  = lane & 15;
  const int m0   = blockIdx.x * 128;
  const int n0   = blockIdx.y * 128;

  __shared__ alignas(16) h16 As[128 * 64];  // unpadded, XOR-swizzled chunks
  __shared__ alignas(16) h16 Bs[128 * 64];

  const f32x4 zero = {0.f, 0.f, 0.f, 0.f};
  f32x4 acc[4][4];
#pragma unroll
  for (int i = 0; i < 4; i++)
#pragma unroll
    for (int j = 0; j < 4; j++) acc[i][j] = zero;

  const int wm = (w >> 1) * 64;
  const int wn = (w & 1) * 64;
  const int sw = l16 & 7;             // read-side swizzle key

  for (int kt = 0; kt < K; kt += 64) {
    // stage 128x64: 1024 chunks per matrix, 4 glds per wave each
#pragma unroll
    for (int p = 0; p < 4; p++) {
      int c   = w * 256 + p * 64 + lane;
      int row = c >> 3;
      int cc  = (c & 7) ^ (row & 7);
      gload16(&A[(size_t)(m0 + row) * K + kt + cc * 8],
              &As[(w * 256 + p * 64) * 8]);
      gload16(&BT[(size_t)(n0 + row) * K + kt + cc * 8],
              &Bs[(w * 256 + p * 64) * 8]);
    }
    __syncthreads();
#pragma unroll
    for (int kk = 0; kk < 2; kk++) {
      h8 af[4], bfr[4];
#pragma unroll
      for (int i = 0; i < 4; i++)
        af[i] = *(const h8*)(&As[(wm + i * 16 + l16) * 64 +
                                 ((kk * 4 + quad) ^ sw) * 8]);
#pragma unroll
      for (int j = 0; j < 4; j++)
        bfr[j] = *(const h8*)(&Bs[(wn + j * 16 + l16) * 64 +
                                  ((kk * 4 + quad) ^ sw) * 8]);
#pragma unroll
      for (int i = 0; i < 4; i++)
#pragma unroll
        for (int j = 0; j < 4; j++)
          acc[i][j] = __builtin_amdgcn_mfma_f32_16x16x32_f16(af[i], bfr[j],
                                                             acc[i][j], 0, 0, 0);
    }
    __syncthreads();
  }

  // epilogue
#pragma unroll
  for (int i = 0; i < 4; i++) {
#pragma unroll
    for (int j = 0; j < 4; j++) {
      int n = n0 + wn + j * 16 + l16;
      float bv = (float)bias[n];
#pragma unroll
      for (int r = 0; r < 4; r++) {
        int m = m0 + wm + i * 16 + quad * 4 + r;
        float v = acc[i][j][r] + bv;
        if (MODE == 0) {
          h16* q0 = (h16*)out0v;
          int which = n >> 10;          // 0=Q, 1=K, 2=V
          int h  = (n >> 6) & 15;
          int hd = n & 63;
          int b  = m >> 11;
          int s  = m & 2047;
          if (which == 0) {
            q0[(((size_t)(b * 16 + h)) * S_ + s) * HD_ + hd] = (h16)(v * QSCALE);
          } else {
            int pos = posmap[b * S_ + s];
            if (pos >= 0) {
              if (which == 1)  // compacted K: (bh, pos, hd)
                out1[(((size_t)(b * 16 + h)) * S_ + pos) * HD_ + hd] = (h16)v;
              else             // compacted V^T: (bh, hd, pos)
                out2[(((size_t)(b * 16 + h)) * HD_ + hd) * S_ + pos] = (h16)v;
            }
          }
        } else {
          ((float*)out0v)[(size_t)m * N + n] = v;
        }
      }
    }
  }
}

// ---------------------------------------------------------------------------
// Flash attention, transposed scores, 64-key tiles, swizzled glds staging.
// grid (S/64, B*H), block 256. S^T = K*Q^T; softmax in exp2 space (Q carries
// log2e); P^T per-wave LDS = PV A-layout.
// ---------------------------------------------------------------------------
__global__ __launch_bounds__(256)
void attn_k(const h16* __restrict__ Q, const h16* __restrict__ Kc,
            const h16* __restrict__ Vtc, const int* __restrict__ nvalid,
            h16* __restrict__ out) {
  const int tid  = threadIdx.x;
  const int lane = tid & 63;
  const int w    = tid >> 6;
  const int quad = lane >> 4;
  const int l16  = lane & 15;
  const int bh   = blockIdx.y;
  const int b    = bh >> 4, h = bh & 15;
  const int q0   = blockIdx.x * 64 + w * 16;
  const int nv   = nvalid[b];
  const int sw   = l16 & 7;

  const h16* Qh = Q   + (size_t)bh * S_ * HD_;
  const h16* Kh = Kc  + (size_t)bh * S_ * HD_;
  const h16* Vh = Vtc + (size_t)bh * HD_ * S_;

  __shared__ alignas(16) h16 Ks[64 * 64];      // [key][hd], swizzled chunks
  __shared__ alignas(16) h16 Vs[64 * 64];      // [hd][key], swizzled chunks
  __shared__ alignas(16) h16 Pb[4][16 * 72];   // per-wave P^T, [q][key]

  h8 bq[2];
#pragma unroll
  for (int ks = 0; ks < 2; ks++)
    bq[ks] = *(const h8*)(&Qh[(size_t)(q0 + l16) * 64 + ks * 32 + quad * 8]);

  const f32x4 zero = {0.f, 0.f, 0.f, 0.f};
  f32x4 oacc[4];
#pragma unroll
  for (int j = 0; j < 4; j++) oacc[j] = zero;
  float mst = -1e30f, lst = 0.f;   // per-lane state for q = q0 + l16

  for (int kb = 0; kb < nv; kb += 64) {
    __syncthreads();
    // stage K (64x64) and V^T (64x64): 512 chunks each, 2 glds/wave each
#pragma unroll
    for (int p = 0; p < 2; p++) {
      int c   = w * 128 + p * 64 + lane;
      int row = c >> 3;
      int cc  = (c & 7) ^ (row & 7);
      gload16(&Kh[(size_t)(kb + row) * 64 + cc * 8],
              &Ks[(w * 128 + p * 64) * 8]);
      gload16(&Vh[(size_t)row * S_ + kb + cc * 8],
              &Vs[(w * 128 + p * 64) * 8]);
    }
    __syncthreads();

    // S^T: st[kh][r] = S[key = kh*16 + quad*4 + r][q = q0 + l16]
    f32x4 st[4];
#pragma unroll
    for (int kh = 0; kh < 4; kh++) {
      h8 ak0 = *(const h8*)(&Ks[(kh * 16 + l16) * 64 + (quad ^ sw) * 8]);
      h8 ak1 = *(const h8*)(&Ks[(kh * 16 + l16) * 64 + ((quad + 4) ^ sw) * 8]);
      f32x4 s = zero;
      s = __builtin_amdgcn_mfma_f32_16x16x32_f16(ak0, bq[0], s, 0, 0, 0);
      s = __builtin_amdgcn_mfma_f32_16x16x32_f16(ak1, bq[1], s, 0, 0, 0);
      st[kh] = s;
    }
    if (kb + 64 > nv) {  // wave-uniform tail mask
#pragma unroll
      for (int kh = 0; kh < 4; kh++)
#pragma unroll
        for (int r = 0; r < 4; r++)
          if (kb + kh * 16 + quad * 4 + r >= nv) st[kh][r] = -1e30f;
    }

    float mx = -1e30f;
#pragma unroll
    for (int kh = 0; kh < 4; kh++)
#pragma unroll
      for (int r = 0; r < 4; r++) mx = fmaxf(mx, st[kh][r]);
    mx = fmaxf(mx, __shfl_xor(mx, 16, 64));
    mx = fmaxf(mx, __shfl_xor(mx, 32, 64));
    float mnew = fmaxf(mst, mx);
    float alpha = EXP2(mst - mnew);         // exp2 space (Q carries log2e)
    float p[4][4], rs = 0.f;
#pragma unroll
    for (int kh = 0; kh < 4; kh++)
#pragma unroll
      for (int r = 0; r < 4; r++) {
        p[kh][r] = EXP2(st[kh][r] - mnew);
        rs += p[kh][r];
      }
    rs += __shfl_xor(rs, 16, 64);
    rs += __shfl_xor(rs, 32, 64);
    lst = lst * alpha + rs;
    mst = mnew;

    float al[4];
#pragma unroll
    for (int r = 0; r < 4; r++) al[r] = __shfl(alpha, quad * 4 + r, 64);
#pragma unroll
    for (int j = 0; j < 4; j++)
#pragma unroll
      for (int r = 0; r < 4; r++) oacc[j][r] *= al[r];

    // P^T -> per-wave LDS [q][key] (stride 72): PV A-layout
    h16* pb = Pb[w];
#pragma unroll
    for (int kh = 0; kh < 4; kh++) {
      h4 pk = {(h16)p[kh][0], (h16)p[kh][1], (h16)p[kh][2], (h16)p[kh][3]};
      *(h4*)(&pb[l16 * 72 + kh * 16 + quad * 4]) = pk;
    }
    h8 pa0 = *(const h8*)(&pb[l16 * 72 + quad * 8]);
    h8 pa1 = *(const h8*)(&pb[l16 * 72 + 32 + quad * 8]);

    // PV: O(16q x 64hd) += P(16q x 64k) * V(64k x 64hd)
#pragma unroll
    for (int j = 0; j < 4; j++) {
      h8 bv0 = *(const h8*)(&Vs[(j * 16 + l16) * 64 + (quad ^ sw) * 8]);
      h8 bv1 = *(const h8*)(&Vs[(j * 16 + l16) * 64 + ((quad + 4) ^ sw) * 8]);
      oacc[j] = __builtin_amdgcn_mfma_f32_16x16x32_f16(pa0, bv0, oacc[j], 0, 0, 0);
      oacc[j] = __builtin_amdgcn_mfma_f32_16x16x32_f16(pa1, bv1, oacc[j], 0, 0, 0);
    }
  }

  float ls[4];
#pragma unroll
  for (int r = 0; r < 4; r++) ls[r] = __shfl(lst, quad * 4 + r, 64);
#pragma unroll
  for (int j = 0; j < 4; j++)
#pragma unroll
    for (int r = 0; r < 4; r++) {
      int row = q0 + quad * 4 + r;
      float v = oacc[j][r] / ls[r];
      out[((size_t)(b * S_ + row)) * D_ + h * 64 + j * 16 + l16] = (h16)v;
    }
}

// ---------------------------------------------------------------------------
// ws (64 MiB, h16): Qb[0,NT) Kc[NT,2NT) Vtc[2NT,3NT) {xc|AOb}[3NT,4NT).
// WouT aliases Qb, boutc aliases Vtc (both written post-attn by post_k).
// d_out scratch (dead before gemm<1>): WinT[0,3.15M) binc@3.4M posmap@24MB.
// Order: prep -> gemm<0> -> attn -> post -> gemm<1>   (5 launches)
// ---------------------------------------------------------------------------
extern "C" void kernel_launch(void* const* d_in, const int* in_sizes, int n_in,
                              void* d_out, int out_size, void* d_ws,
                              size_t ws_size, hipStream_t stream) {
  const float* x     = (const float*)d_in[0];
  const float* w_in  = (const float*)d_in[1];
  const float* b_in  = (const float*)d_in[2];
  const float* w_out = (const float*)d_in[3];
  const float* b_out = (const float*)d_in[4];
  const int*   mask  = (const int*)d_in[5];

  const size_t NT = (size_t)BH_ * S_ * HD_;    // 8,388,608 elems
  h16* ws    = (h16*)d_ws;
  h16* Qb    = ws;
  h16* Kcb   = ws + NT;
  h16* Vtcb  = ws + 2 * NT;
  h16* xc    = ws + 3 * NT;
  h16* AOb   = ws + 3 * NT;
  h16* WouT  = Qb;
  h16* boutc = Vtcb;
  h16* WinT  = (h16*)d_out;
  h16* binc  = (h16*)d_out + 3400704;
  int* posmap = (int*)((char*)d_out + 24u * 1024 * 1024);
  int* nvalid = posmap + B_ * S_;

  prep_k<<<7174, 256, 0, stream>>>(x, w_in, b_in, mask, xc, WinT, binc,
                                   posmap, nvalid);

  gemm_bt<0><<<dim3((B_ * S_) / 128, (3 * D_) / 128), 256, 0, stream>>>(
      xc, WinT, binc, posmap, Qb, Kcb, Vtcb, B_ * S_, 3 * D_, D_);

  attn_k<<<dim3(S_ / 64, BH_), 256, 0, stream>>>(Qb, Kcb, Vtcb, nvalid, AOb);

  post_k<<<1025, 256, 0, stream>>>(w_out, b_out, WouT, boutc);

  gemm_bt<1><<<dim3((B_ * S_) / 128, D_ / 128), 256, 0, stream>>>(
      AOb, WouT, boutc, nullptr, d_out, nullptr, nullptr, B_ * S_, D_, D_);
}